// Round 3
// baseline (282.416 us; speedup 1.0000x reference)
//
#include <hip/hip_runtime.h>
#include <cstdint>
#include <cstddef>

typedef __bf16 bf16x8 __attribute__((ext_vector_type(8)));
typedef float f32x4 __attribute__((ext_vector_type(4)));
typedef float f32x16 __attribute__((ext_vector_type(16)));
typedef unsigned int u32x4 __attribute__((ext_vector_type(4)));
typedef unsigned short u16;
typedef unsigned int u32;

#define S_LEN 4096
#define NH 8
#define DH 64
#define D_EMB 512
#define BATCH 2
#define M_ROWS 8192
#define GK 512
// 0.125 (1/sqrt(dh)) * log2(e): QK^T then runs in log2 domain for exp2
#define QSCALE 0.18033688011112042f

__device__ __forceinline__ u16 f2bf(float f) {
  u32 u = __builtin_bit_cast(u32, f);
  u += 0x7FFFu + ((u >> 16) & 1u);
  return (u16)(u >> 16);
}
__device__ __forceinline__ float bf2f(u16 v) {
  return __builtin_bit_cast(float, (u32)v << 16);
}
__device__ __forceinline__ u32 pk2(float a, float b) {
  return (u32)f2bf(a) | ((u32)f2bf(b) << 16);
}
__device__ __forceinline__ float fexp2(float x) {
#if __has_builtin(__builtin_amdgcn_exp2f)
  return __builtin_amdgcn_exp2f(x);
#else
  return __expf(x * 0.6931471805599453f);  // exp(x*ln2) == 2^x
#endif
}

#define MFMA32(a, b, c) __builtin_amdgcn_mfma_f32_32x32x16_bf16(a, b, c, 0, 0, 0)

#define GLD_LDS16(gsrc, ldst)                                                        \
  __builtin_amdgcn_global_load_lds(                                                  \
      (const __attribute__((address_space(1))) void*)(gsrc),                         \
      (__attribute__((address_space(3))) void*)(ldst), 16, 0, 0)

// ---------------------------------------------------------------------------
// Kernel 0: dtype detect (bf16 -> 0, fp32 -> 1)
// ---------------------------------------------------------------------------
__global__ void detect_kernel(const u16* __restrict__ x, int* __restrict__ flag) {
  __shared__ int cnt;
  if (threadIdx.x == 0) cnt = 0;
  __syncthreads();
  int plaus = 0;
  for (int i = threadIdx.x; i < 2048; i += 256) {
    u16 u = x[2 * i];
    int ex = (u >> 7) & 0xFF;
    plaus += (ex >= 100 && ex <= 134) ? 1 : 0;
  }
  atomicAdd(&cnt, plaus);
  __syncthreads();
  if (threadIdx.x == 0) *flag = (cnt > 1024) ? 0 : 1;
}

// ---------------------------------------------------------------------------
// Kernel 1: pack inputs to bf16 / fp32 workspace copies.
// ---------------------------------------------------------------------------
__global__ void prep_kernel(const void* __restrict__ x, const void* __restrict__ wq,
                            const void* __restrict__ bq, const void* __restrict__ wo,
                            const void* __restrict__ bo,
                            u16* __restrict__ xb, u16* __restrict__ wqb,
                            u16* __restrict__ wob, float* __restrict__ bqf,
                            float* __restrict__ bof, const int* __restrict__ flag) {
  const bool f32 = (*flag != 0);
  const size_t i = (size_t)blockIdx.x * blockDim.x + threadIdx.x;
  if (i < (size_t)M_ROWS * D_EMB)
    xb[i] = f32 ? f2bf(((const float*)x)[i]) : ((const u16*)x)[i];
  if (i < (size_t)3 * D_EMB * D_EMB)
    wqb[i] = f32 ? f2bf(((const float*)wq)[i]) : ((const u16*)wq)[i];
  if (i < (size_t)D_EMB * D_EMB)
    wob[i] = f32 ? f2bf(((const float*)wo)[i]) : ((const u16*)wo)[i];
  if (i < 3 * D_EMB)
    bqf[i] = f32 ? ((const float*)bq)[i] : bf2f(((const u16*)bq)[i]);
  if (i < D_EMB)
    bof[i] = f32 ? ((const float*)bo)[i] : bf2f(((const u16*)bo)[i]);
}

// ---------------------------------------------------------------------------
// GEMM (NT), unchanged structure. EPI 0 scatters q*QSCALE, k, v^T.
// ---------------------------------------------------------------------------
template <int EPI>
__global__ __launch_bounds__(256, 2)
void gemm_bt(const u16* __restrict__ A, const u16* __restrict__ B, int N,
             const float* __restrict__ bias, u16* __restrict__ qout,
             u16* __restrict__ kout, u16* __restrict__ vout, u16* __restrict__ obf,
             float* __restrict__ of32, const int* __restrict__ flag) {
  __shared__ u16 As[128 * 64];
  __shared__ u16 Bs[128 * 64];
  const int tid = threadIdx.x;
  const int wave = tid >> 6, lane = tid & 63;
  const int m0 = blockIdx.x * 128;
  const int n0 = blockIdx.y * 128;
  const int wr = (wave >> 1) * 64, wc = (wave & 1) * 64;

  const int sr = wave * 8 + (lane >> 3);
  const int scb = (lane & 7) * 16;

  f32x4 acc[4][4] = {};

  for (int k0 = 0; k0 < GK; k0 += 64) {
#pragma unroll
    for (int i = 0; i < 4; ++i) {
      const int r = i * 32 + sr;
      const int sc = (scb ^ ((r & 7) << 4)) >> 1;
      GLD_LDS16(A + (size_t)(m0 + r) * GK + k0 + sc, As + i * 2048 + wave * 512);
    }
#pragma unroll
    for (int i = 0; i < 4; ++i) {
      const int r = i * 32 + sr;
      const int sc = (scb ^ ((r & 7) << 4)) >> 1;
      GLD_LDS16(B + (size_t)(n0 + r) * GK + k0 + sc, Bs + i * 2048 + wave * 512);
    }
    __syncthreads();
#pragma unroll
    for (int kk = 0; kk < 2; ++kk) {
      const int cb = kk * 64 + ((lane >> 4) << 4);
      bf16x8 a[4], b[4];
#pragma unroll
      for (int m = 0; m < 4; ++m) {
        const int r = wr + m * 16 + (lane & 15);
        a[m] = *(const bf16x8*)((const char*)As + r * 128 + (cb ^ ((r & 7) << 4)));
      }
#pragma unroll
      for (int n = 0; n < 4; ++n) {
        const int r = wc + n * 16 + (lane & 15);
        b[n] = *(const bf16x8*)((const char*)Bs + r * 128 + (cb ^ ((r & 7) << 4)));
      }
#pragma unroll
      for (int m = 0; m < 4; ++m)
#pragma unroll
        for (int n = 0; n < 4; ++n)
          acc[m][n] = __builtin_amdgcn_mfma_f32_16x16x32_bf16(a[m], b[n], acc[m][n], 0, 0, 0);
    }
    __syncthreads();
  }

  const bool f32out = (EPI == 1) && (*flag != 0);
#pragma unroll
  for (int n = 0; n < 4; ++n) {
    const int col = n0 + wc + n * 16 + (lane & 15);
    const float bv = bias[col];
#pragma unroll
    for (int m = 0; m < 4; ++m) {
#pragma unroll
      for (int r = 0; r < 4; ++r) {
        const int row = m0 + wr + m * 16 + ((lane >> 4) << 2) + r;
        float v = acc[m][n][r] + bv;
        if (EPI == 0) {
          const int b = row >> 12, s = row & 4095;
          const int which = col >> 9, hc = col & 511;
          const int h = hc >> 6, d = hc & 63;
          const size_t bh = (size_t)(b * NH + h);
          if (which == 0) {
            qout[(bh * S_LEN + s) * DH + d] = f2bf(v * QSCALE);
          } else if (which == 1) {
            kout[(bh * S_LEN + s) * DH + d] = f2bf(v);
          } else {
            vout[(bh * DH + d) * S_LEN + s] = f2bf(v);
          }
        } else {
          if (f32out)
            of32[(size_t)row * D_EMB + col] = v;
          else
            obf[(size_t)row * D_EMB + col] = f2bf(v);
        }
      }
    }
  }
}

// ---------------------------------------------------------------------------
// Flash attention, round 3: swapped QK^T (mfma 32x32x16), LDS-free.
// 4 warps/block, 32 q-rows/warp (QBLK=128), KVBLK=64. K/V fragments loaded
// global->VGPR (L2-resident; XCD-partitioned block swizzle). In-register
// softmax (lane owns P row for q=lane&31), T12 pack+swap, T13 defer-max.
// ---------------------------------------------------------------------------
__global__ __launch_bounds__(256, 2)
void flash_attn(const u16* __restrict__ q, const u16* __restrict__ k,
                const u16* __restrict__ vt, u16* __restrict__ ao) {
  // bijective swizzle: XCD x owns bh {2x, 2x+1} (hw xcd = blockIdx % 8)
  const int phys = blockIdx.x;
  const int xcd = phys & 7, slot = phys >> 3;
  const int bh = xcd * 2 + (slot >> 5);
  const int qb = slot & 31;
  const int b = bh >> 3, h = bh & 7;

  const int lane = threadIdx.x & 63;
  const int wave = threadIdx.x >> 6;
  const int l31 = lane & 31, hi = lane >> 5;
  const int q0 = qb * 128 + wave * 32;

  const u16* qp = q + (size_t)bh * S_LEN * DH;
  const u16* kp = k + (size_t)bh * S_LEN * DH;
  const u16* vp = vt + (size_t)bh * DH * S_LEN;

  // Q as B-operand: qf[dk] = Q[q0+l31][dk*16 + 8*hi .. +8]
  bf16x8 qf[4];
  {
    const u16* qrow = qp + (size_t)(q0 + l31) * DH + 8 * hi;
    qf[0] = *(const bf16x8*)(qrow);
    qf[1] = *(const bf16x8*)(qrow + 16);
    qf[2] = *(const bf16x8*)(qrow + 32);
    qf[3] = *(const bf16x8*)(qrow + 48);
  }

  f32x16 accO0 = {}, accO1 = {};
  float m = -1e30f, lst = 0.f;

  const u16* kbase = kp + (size_t)l31 * DH + 8 * hi;      // A-frag row base
  const u16* vbase0 = vp + (size_t)l31 * S_LEN + 8 * hi;  // B-frag (d 0-31)
  const u16* vbase1 = vbase0 + (size_t)32 * S_LEN;        // B-frag (d 32-63)

#pragma unroll 1
  for (int kv0 = 0; kv0 < S_LEN; kv0 += 64) {
    // --- load K/V fragments straight from global (L1/L2-served) ---
    const u16* krow0 = kbase + (size_t)kv0 * DH;
    const u16* krow1 = krow0 + 32 * DH;
    bf16x8 kf0[4], kf1[4], vf0[4], vf1[4];
#pragma unroll
    for (int i = 0; i < 4; ++i) {
      kf0[i] = *(const bf16x8*)(krow0 + i * 16);
      kf1[i] = *(const bf16x8*)(krow1 + i * 16);
      vf0[i] = *(const bf16x8*)(vbase0 + kv0 + i * 16);
      vf1[i] = *(const bf16x8*)(vbase1 + kv0 + i * 16);
    }

    // --- QK^T (swapped): s = K * Q^T, C[kv][q], col=q=l31 ---
    f32x16 s0 = {}, s1 = {};
#pragma unroll
    for (int dk = 0; dk < 4; ++dk) {
      s0 = MFMA32(kf0[dk], qf[dk], s0);
      s1 = MFMA32(kf1[dk], qf[dk], s1);
    }

    // --- row max (own 32 values, log-depth tree) + cross-half combine ---
    float mx16[16];
#pragma unroll
    for (int i = 0; i < 16; ++i) mx16[i] = fmaxf(s0[i], s1[i]);
    float mx8[8];
#pragma unroll
    for (int i = 0; i < 8; ++i) mx8[i] = fmaxf(mx16[i], mx16[i + 8]);
    float mx4[4];
#pragma unroll
    for (int i = 0; i < 4; ++i) mx4[i] = fmaxf(mx8[i], mx8[i + 4]);
    const float mown = fmaxf(fmaxf(mx4[0], mx4[1]), fmaxf(mx4[2], mx4[3]));
    const float pf = fmaxf(mown, __shfl_xor(mown, 32, 64));

    // --- T13 defer-max: rescale only when max grew past threshold ---
    if (!__all(pf - m <= 8.0f)) {
      const float mn = fmaxf(m, pf);
      const float alpha = fexp2(m - mn);
      m = mn;
      lst *= alpha;
#pragma unroll
      for (int r = 0; r < 16; ++r) {
        const int qrow = (r & 3) + 8 * (r >> 2) + 4 * hi;
        const float ar = __shfl(alpha, qrow, 64);
        accO0[r] *= ar;
        accO1[r] *= ar;
      }
    }

    // --- P = exp2(s - m), row sum ---
#pragma unroll
    for (int i = 0; i < 16; ++i) {
      s0[i] = fexp2(s0[i] - m);
      s1[i] = fexp2(s1[i] - m);
    }
    float sm16[16];
#pragma unroll
    for (int i = 0; i < 16; ++i) sm16[i] = s0[i] + s1[i];
    float sm8[8];
#pragma unroll
    for (int i = 0; i < 8; ++i) sm8[i] = sm16[i] + sm16[i + 8];
    float sm4[4];
#pragma unroll
    for (int i = 0; i < 4; ++i) sm4[i] = sm8[i] + sm8[i + 4];
    const float sown = (sm4[0] + sm4[1]) + (sm4[2] + sm4[3]);
    lst += sown + __shfl_xor(sown, 32, 64);

    // --- T12: pack P to bf16 A-fragments, one swap fills both halves ---
    // PACK8 over 8 regs (=16 kv per half-pair); identical words serve lo/hi.
    u32 W0, W1, W2, W3;
#define PACK8(P, B0)                                                   \
    {                                                                  \
      const u32 w0 = pk2(P[B0 + 0], P[B0 + 1]);                        \
      const u32 w1 = pk2(P[B0 + 2], P[B0 + 3]);                        \
      const u32 w2 = pk2(P[B0 + 4], P[B0 + 5]);                        \
      const u32 w3 = pk2(P[B0 + 6], P[B0 + 7]);                        \
      const u32 rA = (u32)__shfl_xor((int)(hi ? w0 : w2), 32, 64);     \
      const u32 rB = (u32)__shfl_xor((int)(hi ? w1 : w3), 32, 64);     \
      W0 = hi ? rA : w0;                                               \
      W1 = hi ? rB : w1;                                               \
      W2 = hi ? w2 : rA;                                               \
      W3 = hi ? w3 : rB;                                               \
    }

    bf16x8 pa;
    PACK8(s0, 0);  // kv 0..15
    pa = __builtin_bit_cast(bf16x8, (u32x4){W0, W1, W2, W3});
    accO0 = MFMA32(pa, vf0[0], accO0);
    accO1 = MFMA32(pa, vf1[0], accO1);
    PACK8(s0, 8);  // kv 16..31
    pa = __builtin_bit_cast(bf16x8, (u32x4){W0, W1, W2, W3});
    accO0 = MFMA32(pa, vf0[1], accO0);
    accO1 = MFMA32(pa, vf1[1], accO1);
    PACK8(s1, 0);  // kv 32..47
    pa = __builtin_bit_cast(bf16x8, (u32x4){W0, W1, W2, W3});
    accO0 = MFMA32(pa, vf0[2], accO0);
    accO1 = MFMA32(pa, vf1[2], accO1);
    PACK8(s1, 8);  // kv 48..63
    pa = __builtin_bit_cast(bf16x8, (u32x4){W0, W1, W2, W3});
    accO0 = MFMA32(pa, vf0[3], accO0);
    accO1 = MFMA32(pa, vf1[3], accO1);
#undef PACK8
  }

  // --- epilogue: O[q][d] / l[q]; broadcast linv to O's row layout ---
  const float linv = 1.f / lst;
#pragma unroll
  for (int r = 0; r < 16; ++r) {
    const int qrow = (r & 3) + 8 * (r >> 2) + 4 * hi;
    const float li = __shfl(linv, qrow, 64);
    u16* orow = ao + (size_t)(b * S_LEN + q0 + qrow) * D_EMB + h * DH;
    orow[l31] = f2bf(accO0[r] * li);
    orow[32 + l31] = f2bf(accO1[r] * li);
  }
}

// ---------------------------------------------------------------------------
extern "C" void kernel_launch(void* const* d_in, const int* in_sizes, int n_in,
                              void* d_out, int out_size, void* d_ws, size_t ws_size,
                              hipStream_t stream) {
  char* w = (char*)d_ws;
  int* flag = (int*)w;
  u16* xb = (u16*)(w + 256);
  u16* wqb = (u16*)(w + 8388864);
  u16* wob = (u16*)(w + 9961728);
  float* bqf = (float*)(w + 10486016);
  float* bof = (float*)(w + 10492160);
  u16* qq = (u16*)(w + 10494208);
  u16* kk = (u16*)(w + 18882816);
  u16* vt = (u16*)(w + 27271424);
  u16* ao = (u16*)(w + 35660032);

  detect_kernel<<<1, 256, 0, stream>>>((const u16*)d_in[0], flag);
  prep_kernel<<<16384, 256, 0, stream>>>(d_in[0], d_in[1], d_in[2], d_in[3], d_in[4],
                                         xb, wqb, wob, bqf, bof, flag);
  gemm_bt<0><<<dim3(64, 12), 256, 0, stream>>>(xb, wqb, 3 * D_EMB, bqf, qq, kk, vt,
                                               nullptr, nullptr, flag);
  flash_attn<<<512, 256, 0, stream>>>(qq, kk, vt, ao);
  gemm_bt<1><<<dim3(64, 4), 256, 0, stream>>>(ao, wob, D_EMB, bof, nullptr, nullptr,
                                              nullptr, (u16*)d_out, (float*)d_out, flag);
}

// Round 4
// 168.508 us; speedup vs baseline: 1.6760x; 1.6760x over previous
//
#include <hip/hip_runtime.h>
#include <cstdint>
#include <cstddef>

typedef __bf16 bf16x8 __attribute__((ext_vector_type(8)));
typedef float f32x4 __attribute__((ext_vector_type(4)));
typedef float f32x16 __attribute__((ext_vector_type(16)));
typedef unsigned int u32x4 __attribute__((ext_vector_type(4)));
typedef unsigned short u16;
typedef unsigned int u32;

#define S_LEN 4096
#define NH 8
#define DH 64
#define D_EMB 512
#define BATCH 2
#define M_ROWS 8192
#define GK 512
// 0.125 (1/sqrt(dh)) * log2(e): QK^T runs in log2 domain for exp2
#define QSCALE 0.18033688011112042f

__device__ __forceinline__ u16 f2bf(float f) {
  u32 u = __builtin_bit_cast(u32, f);
  u += 0x7FFFu + ((u >> 16) & 1u);
  return (u16)(u >> 16);
}
__device__ __forceinline__ float bf2f(u16 v) {
  return __builtin_bit_cast(float, (u32)v << 16);
}
__device__ __forceinline__ u32 pk2(float a, float b) {
  union { __bf16 h[2]; u32 w; } u;
  u.h[0] = (__bf16)a;
  u.h[1] = (__bf16)b;
  return u.w;  // compiler pairs to v_cvt_pk_bf16_f32
}
__device__ __forceinline__ float fexp2(float x) {
#if __has_builtin(__builtin_amdgcn_exp2f)
  return __builtin_amdgcn_exp2f(x);
#else
  return __expf(x * 0.6931471805599453f);
#endif
}

#define MFMA32(a, b, c) __builtin_amdgcn_mfma_f32_32x32x16_bf16(a, b, c, 0, 0, 0)

#define GLD_LDS16(gsrc, ldst)                                                        \
  __builtin_amdgcn_global_load_lds(                                                  \
      (const __attribute__((address_space(1))) void*)(gsrc),                         \
      (__attribute__((address_space(3))) void*)(ldst), 16, 0, 0)

// ---------------------------------------------------------------------------
// Kernel 0: dtype detect (bf16 -> 0, fp32 -> 1)
// ---------------------------------------------------------------------------
__global__ void detect_kernel(const u16* __restrict__ x, int* __restrict__ flag) {
  __shared__ int cnt;
  if (threadIdx.x == 0) cnt = 0;
  __syncthreads();
  int plaus = 0;
  for (int i = threadIdx.x; i < 2048; i += 256) {
    u16 u = x[2 * i];
    int ex = (u >> 7) & 0xFF;
    plaus += (ex >= 100 && ex <= 134) ? 1 : 0;
  }
  atomicAdd(&cnt, plaus);
  __syncthreads();
  if (threadIdx.x == 0) *flag = (cnt > 1024) ? 0 : 1;
}

// ---------------------------------------------------------------------------
// Kernel 1: pack inputs to bf16 / fp32 workspace copies.
// ---------------------------------------------------------------------------
__global__ void prep_kernel(const void* __restrict__ x, const void* __restrict__ wq,
                            const void* __restrict__ bq, const void* __restrict__ wo,
                            const void* __restrict__ bo,
                            u16* __restrict__ xb, u16* __restrict__ wqb,
                            u16* __restrict__ wob, float* __restrict__ bqf,
                            float* __restrict__ bof, const int* __restrict__ flag) {
  const bool f32 = (*flag != 0);
  const size_t i = (size_t)blockIdx.x * blockDim.x + threadIdx.x;
  if (i < (size_t)M_ROWS * D_EMB)
    xb[i] = f32 ? f2bf(((const float*)x)[i]) : ((const u16*)x)[i];
  if (i < (size_t)3 * D_EMB * D_EMB)
    wqb[i] = f32 ? f2bf(((const float*)wq)[i]) : ((const u16*)wq)[i];
  if (i < (size_t)D_EMB * D_EMB)
    wob[i] = f32 ? f2bf(((const float*)wo)[i]) : ((const u16*)wo)[i];
  if (i < 3 * D_EMB)
    bqf[i] = f32 ? ((const float*)bq)[i] : bf2f(((const u16*)bq)[i]);
  if (i < D_EMB)
    bof[i] = f32 ? ((const float*)bo)[i] : bf2f(((const u16*)bo)[i]);
}

// ---------------------------------------------------------------------------
// GEMM (NT). EPI 0 scatters q/k/v directly into MFMA-fragment-major layout:
//   Q/K (A-or-B frag over 32 rows x 64 d): frag[bh][s>>5][d>>4][lane][j]
//        lane = ((d>>3)&1)*32 + (s&31), j = d&7
//   V   (B frag over 16 kv x 32 d):       frag[bh][s>>4][d>>5][lane][j]
//        lane = ((s>>3)&1)*32 + (d&31), j = s&7
// EPI 1 writes the final projection to d_out.
// ---------------------------------------------------------------------------
template <int EPI>
__global__ __launch_bounds__(256, 2)
void gemm_bt(const u16* __restrict__ A, const u16* __restrict__ B, int N,
             const float* __restrict__ bias, u16* __restrict__ qout,
             u16* __restrict__ kout, u16* __restrict__ vout, u16* __restrict__ obf,
             float* __restrict__ of32, const int* __restrict__ flag) {
  __shared__ u16 As[128 * 64];
  __shared__ u16 Bs[128 * 64];
  const int tid = threadIdx.x;
  const int wave = tid >> 6, lane = tid & 63;
  const int m0 = blockIdx.x * 128;
  const int n0 = blockIdx.y * 128;
  const int wr = (wave >> 1) * 64, wc = (wave & 1) * 64;

  const int sr = wave * 8 + (lane >> 3);
  const int scb = (lane & 7) * 16;

  f32x4 acc[4][4] = {};

  for (int k0 = 0; k0 < GK; k0 += 64) {
#pragma unroll
    for (int i = 0; i < 4; ++i) {
      const int r = i * 32 + sr;
      const int sc = (scb ^ ((r & 7) << 4)) >> 1;
      GLD_LDS16(A + (size_t)(m0 + r) * GK + k0 + sc, As + i * 2048 + wave * 512);
    }
#pragma unroll
    for (int i = 0; i < 4; ++i) {
      const int r = i * 32 + sr;
      const int sc = (scb ^ ((r & 7) << 4)) >> 1;
      GLD_LDS16(B + (size_t)(n0 + r) * GK + k0 + sc, Bs + i * 2048 + wave * 512);
    }
    __syncthreads();
#pragma unroll
    for (int kk = 0; kk < 2; ++kk) {
      const int cb = kk * 64 + ((lane >> 4) << 4);
      bf16x8 a[4], b[4];
#pragma unroll
      for (int m = 0; m < 4; ++m) {
        const int r = wr + m * 16 + (lane & 15);
        a[m] = *(const bf16x8*)((const char*)As + r * 128 + (cb ^ ((r & 7) << 4)));
      }
#pragma unroll
      for (int n = 0; n < 4; ++n) {
        const int r = wc + n * 16 + (lane & 15);
        b[n] = *(const bf16x8*)((const char*)Bs + r * 128 + (cb ^ ((r & 7) << 4)));
      }
#pragma unroll
      for (int m = 0; m < 4; ++m)
#pragma unroll
        for (int n = 0; n < 4; ++n)
          acc[m][n] = __builtin_amdgcn_mfma_f32_16x16x32_bf16(a[m], b[n], acc[m][n], 0, 0, 0);
    }
    __syncthreads();
  }

  const bool f32out = (EPI == 1) && (*flag != 0);
#pragma unroll
  for (int n = 0; n < 4; ++n) {
    const int col = n0 + wc + n * 16 + (lane & 15);
    const float bv = bias[col];
#pragma unroll
    for (int m = 0; m < 4; ++m) {
#pragma unroll
      for (int r = 0; r < 4; ++r) {
        const int row = m0 + wr + m * 16 + ((lane >> 4) << 2) + r;
        float v = acc[m][n][r] + bv;
        if (EPI == 0) {
          const int bb = row >> 12, s = row & 4095;
          const int which = col >> 9, hc = col & 511;
          const int h = hc >> 6, d = hc & 63;
          const int bh = bb * NH + h;
          if (which == 2) {
            const int t16 = s >> 4, dblk = d >> 5;
            const int lane_ = ((s >> 3) & 1) * 32 + (d & 31);
            const int j = s & 7;
            vout[(((size_t)(bh * 256 + t16) * 2 + dblk) * 64 + lane_) * 8 + j] = f2bf(v);
          } else {
            const int t32 = s >> 5, dk = d >> 4;
            const int lane_ = ((d >> 3) & 1) * 32 + (s & 31);
            const int j = d & 7;
            u16* dst = (which == 0) ? qout : kout;
            const float vv = (which == 0) ? v * QSCALE : v;
            dst[(((size_t)(bh * 128 + t32) * 4 + dk) * 64 + lane_) * 8 + j] = f2bf(vv);
          }
        } else {
          if (f32out)
            of32[(size_t)row * D_EMB + col] = v;
          else
            obf[(size_t)row * D_EMB + col] = f2bf(v);
        }
      }
    }
  }
}

// ---------------------------------------------------------------------------
// Flash attention, round 4: fragment-major K/V/Q -> every global load is
// base + lane*16B (one coalesced 1KB request). No LDS, no barriers.
// Swapped QK^T (mfma 32x32x16), in-register softmax, T12 pack+swap, T13.
// ---------------------------------------------------------------------------
__global__ __launch_bounds__(256, 2)
void flash_attn(const u16* __restrict__ qfrag, const u16* __restrict__ kfrag,
                const u16* __restrict__ vfrag, u16* __restrict__ ao) {
  // bijective swizzle: XCD x owns bh {2x, 2x+1} (hw xcd = blockIdx % 8)
  const int phys = blockIdx.x;
  const int xcd = phys & 7, slot = phys >> 3;
  const int bh = xcd * 2 + (slot >> 5);
  const int qb = slot & 31;
  const int b = bh >> 3, h = bh & 7;

  const int lane = threadIdx.x & 63;
  const int wave = threadIdx.x >> 6;
  const int l31 = lane & 31, hi = lane >> 5;
  const int q0 = qb * 128 + wave * 32;

  // Q fragments: 4 coalesced 1KB loads, in registers for the whole KV loop
  bf16x8 qf[4];
  {
    const u16* qb_ = qfrag + ((size_t)(bh * 128 + (q0 >> 5)) * 4) * 512 + lane * 8;
#pragma unroll
    for (int dk = 0; dk < 4; ++dk) qf[dk] = *(const bf16x8*)(qb_ + dk * 512);
  }

  const u16* kb_ = kfrag + (size_t)bh * (128 * 4 * 512) + lane * 8;
  const u16* vb_ = vfrag + (size_t)bh * (256 * 2 * 512) + lane * 8;

  f32x16 accO0 = {}, accO1 = {};
  float m = -1e30f, lst = 0.f;

#pragma unroll 1
  for (int kv0 = 0; kv0 < S_LEN; kv0 += 64) {
    const int t32 = kv0 >> 5, t16 = kv0 >> 4;
    bf16x8 kf0[4], kf1[4], vf0[4], vf1[4];
#pragma unroll
    for (int dk = 0; dk < 4; ++dk) {
      kf0[dk] = *(const bf16x8*)(kb_ + (size_t)(t32 * 4 + dk) * 512);
      kf1[dk] = *(const bf16x8*)(kb_ + (size_t)((t32 + 1) * 4 + dk) * 512);
    }
#pragma unroll
    for (int i = 0; i < 4; ++i) {
      vf0[i] = *(const bf16x8*)(vb_ + (size_t)((t16 + i) * 2 + 0) * 512);
      vf1[i] = *(const bf16x8*)(vb_ + (size_t)((t16 + i) * 2 + 1) * 512);
    }

    // --- QK^T (swapped): C[kv][q], col=q=l31 ---
    f32x16 s0 = {}, s1 = {};
#pragma unroll
    for (int dk = 0; dk < 4; ++dk) {
      s0 = MFMA32(kf0[dk], qf[dk], s0);
      s1 = MFMA32(kf1[dk], qf[dk], s1);
    }

    // --- row max (log-depth tree) + cross-half combine ---
    float mx16[16];
#pragma unroll
    for (int i = 0; i < 16; ++i) mx16[i] = fmaxf(s0[i], s1[i]);
    float mx8[8];
#pragma unroll
    for (int i = 0; i < 8; ++i) mx8[i] = fmaxf(mx16[i], mx16[i + 8]);
    float mx4[4];
#pragma unroll
    for (int i = 0; i < 4; ++i) mx4[i] = fmaxf(mx8[i], mx8[i + 4]);
    const float mown = fmaxf(fmaxf(mx4[0], mx4[1]), fmaxf(mx4[2], mx4[3]));
    const float pf = fmaxf(mown, __shfl_xor(mown, 32, 64));

    // --- T13 defer-max ---
    if (!__all(pf - m <= 8.0f)) {
      const float mn = fmaxf(m, pf);
      const float alpha = fexp2(m - mn);
      m = mn;
      lst *= alpha;
#pragma unroll
      for (int r = 0; r < 16; ++r) {
        const int qrow = (r & 3) + 8 * (r >> 2) + 4 * hi;
        const float ar = __shfl(alpha, qrow, 64);
        accO0[r] *= ar;
        accO1[r] *= ar;
      }
    }

    // --- P = exp2(s - m), row sum ---
#pragma unroll
    for (int i = 0; i < 16; ++i) {
      s0[i] = fexp2(s0[i] - m);
      s1[i] = fexp2(s1[i] - m);
    }
    float sm16[16];
#pragma unroll
    for (int i = 0; i < 16; ++i) sm16[i] = s0[i] + s1[i];
    float sm8[8];
#pragma unroll
    for (int i = 0; i < 8; ++i) sm8[i] = sm16[i] + sm16[i + 8];
    float sm4[4];
#pragma unroll
    for (int i = 0; i < 4; ++i) sm4[i] = sm8[i] + sm8[i + 4];
    const float sown = (sm4[0] + sm4[1]) + (sm4[2] + sm4[3]);
    lst += sown + __shfl_xor(sown, 32, 64);

    // --- T12: pack P to bf16 A-fragments, one swap fills both halves ---
    u32 W0, W1, W2, W3;
#define PACK8(P, B0)                                                   \
    {                                                                  \
      const u32 w0 = pk2(P[B0 + 0], P[B0 + 1]);                        \
      const u32 w1 = pk2(P[B0 + 2], P[B0 + 3]);                        \
      const u32 w2 = pk2(P[B0 + 4], P[B0 + 5]);                        \
      const u32 w3 = pk2(P[B0 + 6], P[B0 + 7]);                        \
      const u32 rA = (u32)__shfl_xor((int)(hi ? w0 : w2), 32, 64);     \
      const u32 rB = (u32)__shfl_xor((int)(hi ? w1 : w3), 32, 64);     \
      W0 = hi ? rA : w0;                                               \
      W1 = hi ? rB : w1;                                               \
      W2 = hi ? w2 : rA;                                               \
      W3 = hi ? w3 : rB;                                               \
    }

    bf16x8 pa;
    PACK8(s0, 0);  // kv 0..15
    pa = __builtin_bit_cast(bf16x8, (u32x4){W0, W1, W2, W3});
    accO0 = MFMA32(pa, vf0[0], accO0);
    accO1 = MFMA32(pa, vf1[0], accO1);
    PACK8(s0, 8);  // kv 16..31
    pa = __builtin_bit_cast(bf16x8, (u32x4){W0, W1, W2, W3});
    accO0 = MFMA32(pa, vf0[1], accO0);
    accO1 = MFMA32(pa, vf1[1], accO1);
    PACK8(s1, 0);  // kv 32..47
    pa = __builtin_bit_cast(bf16x8, (u32x4){W0, W1, W2, W3});
    accO0 = MFMA32(pa, vf0[2], accO0);
    accO1 = MFMA32(pa, vf1[2], accO1);
    PACK8(s1, 8);  // kv 48..63
    pa = __builtin_bit_cast(bf16x8, (u32x4){W0, W1, W2, W3});
    accO0 = MFMA32(pa, vf0[3], accO0);
    accO1 = MFMA32(pa, vf1[3], accO1);
#undef PACK8
  }

  // --- epilogue: O[q][d] / l[q] ---
  const float linv = 1.f / lst;
#pragma unroll
  for (int r = 0; r < 16; ++r) {
    const int qrow = (r & 3) + 8 * (r >> 2) + 4 * hi;
    const float li = __shfl(linv, qrow, 64);
    u16* orow = ao + (size_t)(b * S_LEN + q0 + qrow) * D_EMB + h * DH;
    orow[l31] = f2bf(accO0[r] * li);
    orow[32 + l31] = f2bf(accO1[r] * li);
  }
}

// ---------------------------------------------------------------------------
extern "C" void kernel_launch(void* const* d_in, const int* in_sizes, int n_in,
                              void* d_out, int out_size, void* d_ws, size_t ws_size,
                              hipStream_t stream) {
  char* w = (char*)d_ws;
  int* flag = (int*)w;
  u16* xb = (u16*)(w + 256);
  u16* wqb = (u16*)(w + 8388864);
  u16* wob = (u16*)(w + 9961728);
  float* bqf = (float*)(w + 10486016);
  float* bof = (float*)(w + 10492160);
  u16* qfr = (u16*)(w + 10494208);
  u16* kfr = (u16*)(w + 18882816);
  u16* vfr = (u16*)(w + 27271424);
  u16* ao = (u16*)(w + 35660032);

  detect_kernel<<<1, 256, 0, stream>>>((const u16*)d_in[0], flag);
  prep_kernel<<<16384, 256, 0, stream>>>(d_in[0], d_in[1], d_in[2], d_in[3], d_in[4],
                                         xb, wqb, wob, bqf, bof, flag);
  gemm_bt<0><<<dim3(64, 12), 256, 0, stream>>>(xb, wqb, 3 * D_EMB, bqf, qfr, kfr, vfr,
                                               nullptr, nullptr, flag);
  flash_attn<<<512, 256, 0, stream>>>(qfr, kfr, vfr, ao);
  gemm_bt<1><<<dim3(64, 4), 256, 0, stream>>>(ao, wob, D_EMB, bof, nullptr, nullptr,
                                              nullptr, (u16*)d_out, (float*)d_out, flag);
}